// Round 8
// baseline (742.708 us; speedup 1.0000x reference)
//
#include <hip/hip_runtime.h>
#include <hip/hip_bf16.h>

typedef __attribute__((ext_vector_type(8))) short bf16x8; // 8 bf16 in 4 VGPRs
typedef __attribute__((ext_vector_type(4))) float f32x4;

#define MFMA16(a, b, c) __builtin_amdgcn_mfma_f32_16x16x32_bf16(a, b, c, 0, 0, 0)

static constexpr int S  = 4096;
static constexpr int Dm = 512;
static constexpr int Hh = 256;
static constexpr int Bb = 4;

// Swizzled LDS index helpers (bf16 element units; 16B slot granularity).
__device__ __forceinline__ int idx256(int r, int c) { return r * 256 + (c ^ ((r & 7) << 3)); }
__device__ __forceinline__ int idx64 (int r, int c) { return r * 64  + (c ^ ((r & 7) << 3)); }

// ---------------------------------------------------------------------------
// Projection GEMM with depth-1 register prefetch + LDS double-buffer (kept).
// ---------------------------------------------------------------------------
__global__ __launch_bounds__(256) void proj_kernel(
    const float* __restrict__ X,
    const float* __restrict__ W,
    const float* __restrict__ bias,
    __hip_bfloat16* __restrict__ out,
    int N, float scale, int transpose_out)
{
    __shared__ __hip_bfloat16 a_lds[2][64][32];
    __shared__ __hip_bfloat16 w_lds[2][64][32];

    const int tid  = threadIdx.x;
    const int lane = tid & 63;
    const int wave = tid >> 6;
    const int lr   = lane & 15;
    const int lg   = lane >> 4;
    const int m0   = blockIdx.y * 64;
    const int n0   = blockIdx.x * 64;

    const int arow = tid >> 2, aoff = (tid & 3) * 8;
    const int wkk  = tid >> 3, wnoff = (tid & 7) * 8;
    const float* asrc = X + (size_t)(m0 + arow) * 512 + aoff;
    const float* wsrc = W + (size_t)wkk * N + n0 + wnoff;

    f32x4 acc[4];
    #pragma unroll
    for (int n = 0; n < 4; ++n) acc[n] = (f32x4){0.f, 0.f, 0.f, 0.f};

    {
        float ar[8], wr[8];
        #pragma unroll
        for (int j = 0; j < 8; ++j) { ar[j] = asrc[j]; wr[j] = wsrc[j]; }
        #pragma unroll
        for (int j = 0; j < 8; ++j) a_lds[0][arow][aoff + j] = __float2bfloat16(ar[j]);
        #pragma unroll
        for (int j = 0; j < 8; ++j) w_lds[0][wnoff + j][wkk] = __float2bfloat16(wr[j]);
    }
    __syncthreads();

    int cur = 0;
    for (int k0 = 0; k0 < 512; k0 += 32) {
        float ar[8], wr[8];
        if (k0 < 480) {
            #pragma unroll
            for (int j = 0; j < 8; ++j) ar[j] = asrc[k0 + 32 + j];
            #pragma unroll
            for (int j = 0; j < 8; ++j) wr[j] = wsrc[(size_t)(k0 + 32) * N + j];
        }
        bf16x8 af = *(const bf16x8*)&a_lds[cur][wave * 16 + lr][lg * 8];
        __builtin_amdgcn_s_setprio(1);
        #pragma unroll
        for (int n = 0; n < 4; ++n) {
            bf16x8 bfr = *(const bf16x8*)&w_lds[cur][n * 16 + lr][lg * 8];
            acc[n] = MFMA16(af, bfr, acc[n]);
        }
        __builtin_amdgcn_s_setprio(0);
        if (k0 < 480) {
            #pragma unroll
            for (int j = 0; j < 8; ++j) a_lds[cur ^ 1][arow][aoff + j] = __float2bfloat16(ar[j]);
            #pragma unroll
            for (int j = 0; j < 8; ++j) w_lds[cur ^ 1][wnoff + j][wkk] = __float2bfloat16(wr[j]);
        }
        __syncthreads();
        cur ^= 1;
    }

    #pragma unroll
    for (int n = 0; n < 4; ++n) {
        int col = n0 + n * 16 + lr;
        float bia = bias[col];
        #pragma unroll
        for (int r = 0; r < 4; ++r) {
            int row = m0 + wave * 16 + lg * 4 + r;
            float val = (acc[n][r] + bia) * scale;
            if (!transpose_out) {
                out[(size_t)row * N + col] = __float2bfloat16(val);
            } else {
                int bidx = row >> 12, s = row & 4095;
                out[((size_t)bidx * N + col) * S + s] = __float2bfloat16(val);
            }
        }
    }
}

// ---------------------------------------------------------------------------
// lsum_kernel: QK^T + exp -> partial row sums (kv-quarter per block).
// Flat grid 1024, XCD-decoded: logical = (bx&7)*128 + (bx>>3);
//   b = logical>>8, kvq = (logical>>6)&3, q0 = (logical&63)*64.
// 8 waves: qg=w>>1 owns q-rows [16qg,+16); half=w&1 owns kv cols [32half,+32).
// 16 kt per block. LDS 32.5 KB -> 4 blocks/CU.
// ---------------------------------------------------------------------------
__global__ __launch_bounds__(512, 4) void lsum_kernel(
    const __hip_bfloat16* __restrict__ Q,   // [B][S][H], pre-scaled
    const __hip_bfloat16* __restrict__ K,   // [B][S][H]
    float* __restrict__ l_ws)               // [B][S][4] partial row sums
{
    __shared__ __hip_bfloat16 k_lds[64 * 256];  // 32 KB (swizzled)
    __shared__ float stats_lds[2][4][16];

    const int bx      = blockIdx.x;
    const int logical = (bx & 7) * 128 + (bx >> 3);
    const int b       = logical >> 8;
    const int kvq     = (logical >> 6) & 3;
    const int q0      = (logical & 63) * 64;

    const int tid  = threadIdx.x;
    const int lane = tid & 63;
    const int w    = tid >> 6;
    const int lr   = lane & 15;
    const int lg   = lane >> 4;
    const int qg   = w >> 1;
    const int half = w & 1;

    const __hip_bfloat16* Qb = Q + ((size_t)b * S + q0) * Hh;
    const __hip_bfloat16* Kb = K + (size_t)b * S * Hh;

    const int krow = tid >> 3, kcb = (tid & 7) * 8;

    bf16x8 qf[8];
    #pragma unroll
    for (int h = 0; h < 8; ++h)
        qf[h] = *(const bf16x8*)&Qb[(size_t)(qg * 16 + lr) * Hh + h * 32 + lg * 8];

    float lsum[4] = {0.f, 0.f, 0.f, 0.f};

    for (int kt = kvq * 16; kt < kvq * 16 + 16; ++kt) {
        uint4 kr[4];
        const __hip_bfloat16* src = Kb + (size_t)(kt * 64 + krow) * Hh + kcb;
        #pragma unroll
        for (int c0 = 0; c0 < 4; ++c0) kr[c0] = *(const uint4*)&src[c0 * 64];
        __syncthreads();  // previous tile's readers done
        #pragma unroll
        for (int c0 = 0; c0 < 4; ++c0)
            *(uint4*)&k_lds[idx256(krow, kcb + c0 * 64)] = kr[c0];
        __syncthreads();

        f32x4 acc[2];
        #pragma unroll
        for (int nn = 0; nn < 2; ++nn) acc[nn] = (f32x4){0.f, 0.f, 0.f, 0.f};
        __builtin_amdgcn_s_setprio(1);
        #pragma unroll
        for (int nn = 0; nn < 2; ++nn) {
            int n = half * 2 + nn;
            #pragma unroll
            for (int h = 0; h < 8; ++h) {
                bf16x8 kf = *(const bf16x8*)&k_lds[idx256(n * 16 + lr, h * 32 + lg * 8)];
                acc[nn] = MFMA16(qf[h], kf, acc[nn]);
            }
        }
        __builtin_amdgcn_s_setprio(0);
        #pragma unroll
        for (int r = 0; r < 4; ++r)
            lsum[r] += __expf(acc[0][r]) + __expf(acc[1][r]);
    }

    #pragma unroll
    for (int r = 0; r < 4; ++r)
        #pragma unroll
        for (int m = 1; m < 16; m <<= 1) lsum[r] += __shfl_xor(lsum[r], m);
    if (lr == 0) {
        #pragma unroll
        for (int r = 0; r < 4; ++r) stats_lds[half][qg][lg * 4 + r] = lsum[r];
    }
    __syncthreads();
    if (half == 0 && lr == 0) {
        #pragma unroll
        for (int r = 0; r < 4; ++r) {
            int row = q0 + qg * 16 + lg * 4 + r;
            l_ws[((size_t)(b * S + row)) * 4 + kvq] =
                lsum[r] + stats_lds[1][qg][lg * 4 + r];
        }
    }
}

// ---------------------------------------------------------------------------
// pv_kernel: D-split fused pass. Flat grid 512, XCD-decoded:
//   logical = (bx&7)*64 + (bx>>3); b = logical>>7; dh = (logical>>6)&1;
//   q0 = (logical&63)*64.
// Each block: 64 q-rows, FULL kv sweep (64 kt), d-half [256*dh, +256).
// QK computed by both d-halves (redundant, cheap); attn stored by dh==0 only;
// PV + out on own d-half (disjoint -> no atomics).
// Per kt: b0 -> stage K(32K)+VT-half(32K) -> b1 -> QK -> softmax+attn+P -> b2
//         -> PV. 3 barriers/kt. LDS 72.5 KB -> 2 blocks/CU.
// ---------------------------------------------------------------------------
__global__ __launch_bounds__(512, 2) void pv_kernel(
    const __hip_bfloat16* __restrict__ Q,   // [B][S][H], pre-scaled
    const __hip_bfloat16* __restrict__ K,   // [B][S][H]
    const __hip_bfloat16* __restrict__ VT,  // [B][D][S]
    const float* __restrict__ l_ws,         // [B][S][4]
    float* __restrict__ out,                // [B][S][D]
    float* __restrict__ attn)               // [B][S][S]
{
    __shared__ __align__(16) char smem[74240];
    __hip_bfloat16* k_lds  = (__hip_bfloat16*)smem;            // [64][256] 32 KB
    __hip_bfloat16* vt_lds = (__hip_bfloat16*)(smem + 32768);  // [256][64] 32 KB
    __hip_bfloat16* p_lds  = (__hip_bfloat16*)(smem + 65536);  // [64][64]   8 KB

    const int bx      = blockIdx.x;
    const int logical = (bx & 7) * 64 + (bx >> 3);
    const int b       = logical >> 7;
    const int dh      = (logical >> 6) & 1;
    const int q0      = (logical & 63) * 64;

    const int tid  = threadIdx.x;
    const int lane = tid & 63;
    const int w    = tid >> 6;   // 0..7
    const int lr   = lane & 15;
    const int lg   = lane >> 4;
    const int qg   = w >> 1;     // 0..3
    const int half = w & 1;      // 0..1

    const __hip_bfloat16* Qb  = Q  + ((size_t)b * S + q0) * Hh;
    const __hip_bfloat16* Kb  = K  + (size_t)b * S * Hh;
    const __hip_bfloat16* VTb = VT + ((size_t)b * Dm + dh * 256) * S;

    // Q fragments: wave's 16 q-rows over H=256.
    bf16x8 qf[8];
    #pragma unroll
    for (int h = 0; h < 8; ++h)
        qf[h] = *(const bf16x8*)&Qb[(size_t)(qg * 16 + lr) * Hh + h * 32 + lg * 8];

    // inv_l for this thread's 4 q-rows (sum of 4 kv-quarter partials)
    float inv_l[4];
    #pragma unroll
    for (int r = 0; r < 4; ++r) {
        int row = q0 + qg * 16 + lg * 4 + r;
        float4 lp = *(const float4*)&l_ws[((size_t)(b * S + row)) * 4];
        inv_l[r] = 1.0f / (lp.x + lp.y + lp.z + lp.w);
    }

    // staging maps
    const int krow = tid >> 3, kcb = (tid & 7) * 8;   // K [64][256]
    const int vrow = tid >> 3, vcb = (tid & 7) * 8;   // VT [256][64]: 4 rows/thread

    f32x4 oacc[4][2];   // [qt 0..3][dt 0..1], wave's d-slice = [32w, 32w+32) local
    #pragma unroll
    for (int qt = 0; qt < 4; ++qt)
        #pragma unroll
        for (int dt = 0; dt < 2; ++dt) oacc[qt][dt] = (f32x4){0.f, 0.f, 0.f, 0.f};

    for (int kt = 0; kt < 64; ++kt) {
        __syncthreads();  // b0: prev PV + p reads done; LDS free
        {   // stage K tile [64 kv][256 H]
            const __hip_bfloat16* src = Kb + (size_t)(kt * 64 + krow) * Hh + kcb;
            #pragma unroll
            for (int c0 = 0; c0 < 4; ++c0)
                *(uint4*)&k_lds[idx256(krow, kcb + c0 * 64)] = *(const uint4*)&src[c0 * 64];
        }
        {   // stage VT half tile [256 d][64 kv]
            #pragma unroll
            for (int j = 0; j < 4; ++j) {
                int row = j * 64 + vrow;
                *(uint4*)&vt_lds[idx64(row, vcb)] =
                    *(const uint4*)&VTb[(size_t)row * S + kt * 64 + vcb];
            }
        }
        __syncthreads();  // b1

        // QK^T: wave's 16 q-rows x 32 kv cols
        f32x4 acc[2];
        #pragma unroll
        for (int nn = 0; nn < 2; ++nn) acc[nn] = (f32x4){0.f, 0.f, 0.f, 0.f};
        __builtin_amdgcn_s_setprio(1);
        #pragma unroll
        for (int nn = 0; nn < 2; ++nn) {
            int n = half * 2 + nn;
            #pragma unroll
            for (int h = 0; h < 8; ++h) {
                bf16x8 kf = *(const bf16x8*)&k_lds[idx256(n * 16 + lr, h * 32 + lg * 8)];
                acc[nn] = MFMA16(qf[h], kf, acc[nn]);
            }
        }
        __builtin_amdgcn_s_setprio(0);

        // softmax + fuzzy clamp; attn store (dh==0 only) + P (bf16)
        #pragma unroll
        for (int nn = 0; nn < 2; ++nn)
            #pragma unroll
            for (int r = 0; r < 4; ++r) {
                float p = __expf(acc[nn][r]) * inv_l[r];
                float f = fmaxf(fminf(p, 1.0f - p) * (1.0f / 0.3f), 0.0f);
                int row_l = qg * 16 + lg * 4 + r;
                int col_l = (half * 2 + nn) * 16 + lr;
                if (dh == 0)
                    attn[((size_t)(b * S + q0 + row_l)) * S + kt * 64 + col_l] = f;
                p_lds[idx64(row_l, col_l)] = __float2bfloat16(f);
            }
        __syncthreads();  // b2: p_lds ready (K/VT reads for this kt also done issuing)

        // PV: wave w owns local d-slice [32w, 32w+32)
        bf16x8 pf[4][2];
        #pragma unroll
        for (int qt = 0; qt < 4; ++qt)
            #pragma unroll
            for (int ks = 0; ks < 2; ++ks)
                pf[qt][ks] = *(const bf16x8*)&p_lds[idx64(qt * 16 + lr, ks * 32 + lg * 8)];
        __builtin_amdgcn_s_setprio(1);
        #pragma unroll
        for (int dt = 0; dt < 2; ++dt)
            #pragma unroll
            for (int ks = 0; ks < 2; ++ks) {
                bf16x8 vf = *(const bf16x8*)&vt_lds[idx64(w * 32 + dt * 16 + lr, ks * 32 + lg * 8)];
                #pragma unroll
                for (int qt = 0; qt < 4; ++qt)
                    oacc[qt][dt] = MFMA16(pf[qt][ks], vf, oacc[qt][dt]);
            }
        __builtin_amdgcn_s_setprio(0);
    }

    // epilogue: out[B][S][D] fp32, this block's d-half
    #pragma unroll
    for (int qt = 0; qt < 4; ++qt)
        #pragma unroll
        for (int dt = 0; dt < 2; ++dt) {
            int col = dh * 256 + w * 32 + dt * 16 + lr;
            #pragma unroll
            for (int r = 0; r < 4; ++r) {
                int row = q0 + qt * 16 + lg * 4 + r;
                out[((size_t)(b * S + row)) * Dm + col] = oacc[qt][dt][r];
            }
        }
}

// ---------------------------------------------------------------------------
extern "C" void kernel_launch(void* const* d_in, const int* in_sizes, int n_in,
                              void* d_out, int out_size, void* d_ws, size_t ws_size,
                              hipStream_t stream) {
    const float* x  = (const float*)d_in[0];
    const float* Wq = (const float*)d_in[1];
    const float* bq = (const float*)d_in[2];
    const float* Wk = (const float*)d_in[3];
    const float* bk = (const float*)d_in[4];
    const float* Wv = (const float*)d_in[5];
    const float* bv = (const float*)d_in[6];

    float* out  = (float*)d_out;                      // [4,4096,512]
    float* attn = out + (size_t)Bb * S * Dm;          // [4,4096,4096]

    __hip_bfloat16* q_ws  = (__hip_bfloat16*)d_ws;              // [B][S][H]
    __hip_bfloat16* k_ws  = q_ws + (size_t)Bb * S * Hh;         // [B][S][H]
    __hip_bfloat16* vt_ws = k_ws + (size_t)Bb * S * Hh;         // [B][D][S]
    float*          l_ws  = (float*)(vt_ws + (size_t)Bb * Dm * S); // [B][S][4]

    const float scale = 0.0625f;  // 1/sqrt(256)

    proj_kernel<<<dim3(Hh / 64, (Bb * S) / 64), 256, 0, stream>>>(x, Wq, bq, q_ws, Hh, scale, 0);
    proj_kernel<<<dim3(Hh / 64, (Bb * S) / 64), 256, 0, stream>>>(x, Wk, bk, k_ws, Hh, 1.0f, 0);
    proj_kernel<<<dim3(Dm / 64, (Bb * S) / 64), 256, 0, stream>>>(x, Wv, bv, vt_ws, Dm, 1.0f, 1);

    lsum_kernel<<<1024, 512, 0, stream>>>(q_ws, k_ws, l_ws);
    pv_kernel<<<512, 512, 0, stream>>>(q_ws, k_ws, vt_ws, l_ws, out, attn);
}

// Round 9
// 497.198 us; speedup vs baseline: 1.4938x; 1.4938x over previous
//
#include <hip/hip_runtime.h>
#include <hip/hip_bf16.h>

typedef __attribute__((ext_vector_type(8))) short bf16x8;   // 8 bf16
typedef __attribute__((ext_vector_type(4))) float f32x4;
typedef __attribute__((ext_vector_type(16))) float f32x16;

#define MFMA16(a, b, c) __builtin_amdgcn_mfma_f32_16x16x32_bf16(a, b, c, 0, 0, 0)
#define MFMA32(a, b, c) __builtin_amdgcn_mfma_f32_32x32x16_bf16(a, b, c, 0, 0, 0)

static constexpr int S  = 4096;
static constexpr int Dm = 512;
static constexpr int Hh = 256;
static constexpr int Bb = 4;

// Swizzled LDS index helpers (bf16 element units; 16B slot granularity).
__device__ __forceinline__ int idx256(int r, int c) { return r * 256 + (c ^ ((r & 7) << 3)); }
__device__ __forceinline__ int idx64 (int r, int c) { return r * 64  + (c ^ ((r & 7) << 3)); }

// ---------------------------------------------------------------------------
// Projection GEMM with depth-1 register prefetch + LDS double-buffer (kept).
// ---------------------------------------------------------------------------
__global__ __launch_bounds__(256) void proj_kernel(
    const float* __restrict__ X,
    const float* __restrict__ W,
    const float* __restrict__ bias,
    __hip_bfloat16* __restrict__ out,
    int N, float scale, int transpose_out)
{
    __shared__ __hip_bfloat16 a_lds[2][64][32];
    __shared__ __hip_bfloat16 w_lds[2][64][32];

    const int tid  = threadIdx.x;
    const int lane = tid & 63;
    const int wave = tid >> 6;
    const int lr   = lane & 15;
    const int lg   = lane >> 4;
    const int m0   = blockIdx.y * 64;
    const int n0   = blockIdx.x * 64;

    const int arow = tid >> 2, aoff = (tid & 3) * 8;
    const int wkk  = tid >> 3, wnoff = (tid & 7) * 8;
    const float* asrc = X + (size_t)(m0 + arow) * 512 + aoff;
    const float* wsrc = W + (size_t)wkk * N + n0 + wnoff;

    f32x4 acc[4];
    #pragma unroll
    for (int n = 0; n < 4; ++n) acc[n] = (f32x4){0.f, 0.f, 0.f, 0.f};

    {
        float ar[8], wr[8];
        #pragma unroll
        for (int j = 0; j < 8; ++j) { ar[j] = asrc[j]; wr[j] = wsrc[j]; }
        #pragma unroll
        for (int j = 0; j < 8; ++j) a_lds[0][arow][aoff + j] = __float2bfloat16(ar[j]);
        #pragma unroll
        for (int j = 0; j < 8; ++j) w_lds[0][wnoff + j][wkk] = __float2bfloat16(wr[j]);
    }
    __syncthreads();

    int cur = 0;
    for (int k0 = 0; k0 < 512; k0 += 32) {
        float ar[8], wr[8];
        if (k0 < 480) {
            #pragma unroll
            for (int j = 0; j < 8; ++j) ar[j] = asrc[k0 + 32 + j];
            #pragma unroll
            for (int j = 0; j < 8; ++j) wr[j] = wsrc[(size_t)(k0 + 32) * N + j];
        }
        bf16x8 af = *(const bf16x8*)&a_lds[cur][wave * 16 + lr][lg * 8];
        __builtin_amdgcn_s_setprio(1);
        #pragma unroll
        for (int n = 0; n < 4; ++n) {
            bf16x8 bfr = *(const bf16x8*)&w_lds[cur][n * 16 + lr][lg * 8];
            acc[n] = MFMA16(af, bfr, acc[n]);
        }
        __builtin_amdgcn_s_setprio(0);
        if (k0 < 480) {
            #pragma unroll
            for (int j = 0; j < 8; ++j) a_lds[cur ^ 1][arow][aoff + j] = __float2bfloat16(ar[j]);
            #pragma unroll
            for (int j = 0; j < 8; ++j) w_lds[cur ^ 1][wnoff + j][wkk] = __float2bfloat16(wr[j]);
        }
        __syncthreads();
        cur ^= 1;
    }

    #pragma unroll
    for (int n = 0; n < 4; ++n) {
        int col = n0 + n * 16 + lr;
        float bia = bias[col];
        #pragma unroll
        for (int r = 0; r < 4; ++r) {
            int row = m0 + wave * 16 + lg * 4 + r;
            float val = (acc[n][r] + bia) * scale;
            if (!transpose_out) {
                out[(size_t)row * N + col] = __float2bfloat16(val);
            } else {
                int bidx = row >> 12, s = row & 4095;
                out[((size_t)bidx * N + col) * S + s] = __float2bfloat16(val);
            }
        }
    }
}

// ---------------------------------------------------------------------------
// lsum_kernel (v2, 32x32x16 MFMA): QK^T + exp -> partial row sums.
// Flat grid 512, XCD-decoded: logical = (bx&7)*64 + (bx>>3);
//   b = logical>>7, kvq = (logical>>5)&3, q0 = (logical&31)*128.
// 128 q-rows per block; 8 waves = qg(0..3: 32 rows) x cg(0..1: 32 cols).
// Per kt: one 32x32 tile chain per wave (16 MFMA, K=256). Per-lane lsum[16]
// accumulated across kt; single cross-lane reduce at the end.
// C-row mapping (m74): row = (reg&3) + 8*(reg>>2) + 4*(lane>>5).
// LDS 33 KB -> 2 blocks/CU at grid 512.
// ---------------------------------------------------------------------------
__global__ __launch_bounds__(512, 4) void lsum_kernel(
    const __hip_bfloat16* __restrict__ Q,   // [B][S][H], pre-scaled
    const __hip_bfloat16* __restrict__ K,   // [B][S][H]
    float* __restrict__ l_ws)               // [B][S][4] partial row sums
{
    __shared__ __hip_bfloat16 k_lds[64 * 256];  // 32 KB (swizzled)
    __shared__ float stats_lds[2][128];

    const int bx      = blockIdx.x;
    const int logical = (bx & 7) * 64 + (bx >> 3);
    const int b       = logical >> 7;
    const int kvq     = (logical >> 5) & 3;
    const int q0      = (logical & 31) * 128;

    const int tid  = threadIdx.x;
    const int lane = tid & 63;
    const int w    = tid >> 6;
    const int l31  = lane & 31;
    const int hi   = lane >> 5;
    const int qg   = w >> 1;     // 0..3: rows [32qg, +32)
    const int cg   = w & 1;      // 0..1: cols [32cg, +32)

    const __hip_bfloat16* Qb = Q + ((size_t)b * S + q0) * Hh;
    const __hip_bfloat16* Kb = K + (size_t)b * S * Hh;

    // A(Q) fragments: row = qg*32 + l31; step t covers k = t*16 + hi*8 .. +8
    bf16x8 qf[16];
    #pragma unroll
    for (int t = 0; t < 16; ++t)
        qf[t] = *(const bf16x8*)&Qb[(size_t)(qg * 32 + l31) * Hh + t * 16 + hi * 8];

    float lsum[16];
    #pragma unroll
    for (int j = 0; j < 16; ++j) lsum[j] = 0.f;

    const int krow = tid >> 3, kcb = (tid & 7) * 8;

    for (int kt = kvq * 16; kt < kvq * 16 + 16; ++kt) {
        __syncthreads();  // previous tile's readers done
        {   // stage K tile [64 kv][256 H]
            const __hip_bfloat16* src = Kb + (size_t)(kt * 64 + krow) * Hh + kcb;
            #pragma unroll
            for (int c0 = 0; c0 < 4; ++c0)
                *(uint4*)&k_lds[idx256(krow, kcb + c0 * 64)] = *(const uint4*)&src[c0 * 64];
        }
        __syncthreads();

        f32x16 acc;
        #pragma unroll
        for (int j = 0; j < 16; ++j) acc[j] = 0.f;
        __builtin_amdgcn_s_setprio(1);
        #pragma unroll
        for (int t = 0; t < 16; ++t) {
            bf16x8 kf = *(const bf16x8*)&k_lds[idx256(cg * 32 + l31, t * 16 + hi * 8)];
            acc = MFMA32(qf[t], kf, acc);
        }
        __builtin_amdgcn_s_setprio(0);
        #pragma unroll
        for (int j = 0; j < 16; ++j) lsum[j] += __expf(acc[j]);
    }

    // reduce across the 32 columns (lanes sharing hi); rows disjoint by hi.
    #pragma unroll
    for (int j = 0; j < 16; ++j)
        #pragma unroll
        for (int m = 1; m < 32; m <<= 1) lsum[j] += __shfl_xor(lsum[j], m);

    if (l31 == 0) {
        #pragma unroll
        for (int j = 0; j < 16; ++j) {
            int row = qg * 32 + (j & 3) + 8 * (j >> 2) + 4 * hi;
            stats_lds[cg][row] = lsum[j];
        }
    }
    __syncthreads();
    if (tid < 128) {
        l_ws[((size_t)(b * S + q0 + tid)) * 4 + kvq] =
            stats_lds[0][tid] + stats_lds[1][tid];
    }
}

// ---------------------------------------------------------------------------
// pv_kernel: D-split fused pass (R8 structure). Flat grid 512, XCD-decoded:
//   logical = (bx&7)*64 + (bx>>3); b = logical>>7; dh = (logical>>6)&1;
//   q0 = (logical&63)*64.
// launch_bounds (512,4): forces VGPR+AGPR <= 128 -> 2 blocks/CU (R8 fix).
// Per kt: b0 -> stage K -> b1 -> QK -> {stage VT-half | softmax+attn+P} ->
//         b2 -> PV. 3 barriers/kt.
// ---------------------------------------------------------------------------
__global__ __launch_bounds__(512, 4) void pv_kernel(
    const __hip_bfloat16* __restrict__ Q,   // [B][S][H], pre-scaled
    const __hip_bfloat16* __restrict__ K,   // [B][S][H]
    const __hip_bfloat16* __restrict__ VT,  // [B][D][S]
    const float* __restrict__ l_ws,         // [B][S][4]
    float* __restrict__ out,                // [B][S][D]
    float* __restrict__ attn)               // [B][S][S]
{
    __shared__ __align__(16) char smem[73728];
    __hip_bfloat16* k_lds  = (__hip_bfloat16*)smem;            // [64][256] 32 KB
    __hip_bfloat16* vt_lds = (__hip_bfloat16*)(smem + 32768);  // [256][64] 32 KB
    __hip_bfloat16* p_lds  = (__hip_bfloat16*)(smem + 65536);  // [64][64]   8 KB

    const int bx      = blockIdx.x;
    const int logical = (bx & 7) * 64 + (bx >> 3);
    const int b       = logical >> 7;
    const int dh      = (logical >> 6) & 1;
    const int q0      = (logical & 63) * 64;

    const int tid  = threadIdx.x;
    const int lane = tid & 63;
    const int w    = tid >> 6;   // 0..7
    const int lr   = lane & 15;
    const int lg   = lane >> 4;
    const int qg   = w >> 1;     // 0..3
    const int half = w & 1;      // 0..1

    const __hip_bfloat16* Qb  = Q  + ((size_t)b * S + q0) * Hh;
    const __hip_bfloat16* Kb  = K  + (size_t)b * S * Hh;
    const __hip_bfloat16* VTb = VT + ((size_t)b * Dm + dh * 256) * S;

    bf16x8 qf[8];
    #pragma unroll
    for (int h = 0; h < 8; ++h)
        qf[h] = *(const bf16x8*)&Qb[(size_t)(qg * 16 + lr) * Hh + h * 32 + lg * 8];

    float inv_l[4];
    #pragma unroll
    for (int r = 0; r < 4; ++r) {
        int row = q0 + qg * 16 + lg * 4 + r;
        float4 lp = *(const float4*)&l_ws[((size_t)(b * S + row)) * 4];
        inv_l[r] = 1.0f / (lp.x + lp.y + lp.z + lp.w);
    }

    const int krow = tid >> 3, kcb = (tid & 7) * 8;   // K [64][256]
    const int vrow = tid >> 3, vcb = (tid & 7) * 8;   // VT [256][64]: 4 rows/thread

    f32x4 oacc[4][2];   // [qt][dt]; wave's local d-slice [32w, 32w+32)
    #pragma unroll
    for (int qt = 0; qt < 4; ++qt)
        #pragma unroll
        for (int dt = 0; dt < 2; ++dt) oacc[qt][dt] = (f32x4){0.f, 0.f, 0.f, 0.f};

    for (int kt = 0; kt < 64; ++kt) {
        __syncthreads();  // b0: prev PV + P reads done; LDS free
        {   // stage K tile [64 kv][256 H]
            const __hip_bfloat16* src = Kb + (size_t)(kt * 64 + krow) * Hh + kcb;
            #pragma unroll
            for (int c0 = 0; c0 < 4; ++c0)
                *(uint4*)&k_lds[idx256(krow, kcb + c0 * 64)] = *(const uint4*)&src[c0 * 64];
        }
        __syncthreads();  // b1: K ready

        // QK^T: wave's 16 q-rows x 32 kv cols
        f32x4 acc[2];
        #pragma unroll
        for (int nn = 0; nn < 2; ++nn) acc[nn] = (f32x4){0.f, 0.f, 0.f, 0.f};
        __builtin_amdgcn_s_setprio(1);
        #pragma unroll
        for (int nn = 0; nn < 2; ++nn) {
            int n = half * 2 + nn;
            #pragma unroll
            for (int h = 0; h < 8; ++h) {
                bf16x8 kf = *(const bf16x8*)&k_lds[idx256(n * 16 + lr, h * 32 + lg * 8)];
                acc[nn] = MFMA16(qf[h], kf, acc[nn]);
            }
        }
        __builtin_amdgcn_s_setprio(0);

        {   // stage VT half tile [256 d][64 kv] (overlaps softmax below)
            #pragma unroll
            for (int j = 0; j < 4; ++j) {
                int row = j * 64 + vrow;
                *(uint4*)&vt_lds[idx64(row, vcb)] =
                    *(const uint4*)&VTb[(size_t)row * S + kt * 64 + vcb];
            }
        }

        // softmax + fuzzy clamp; attn store (dh==0 only) + P (bf16)
        #pragma unroll
        for (int nn = 0; nn < 2; ++nn)
            #pragma unroll
            for (int r = 0; r < 4; ++r) {
                float p = __expf(acc[nn][r]) * inv_l[r];
                float f = fmaxf(fminf(p, 1.0f - p) * (1.0f / 0.3f), 0.0f);
                int row_l = qg * 16 + lg * 4 + r;
                int col_l = (half * 2 + nn) * 16 + lr;
                if (dh == 0)
                    attn[((size_t)(b * S + q0 + row_l)) * S + kt * 64 + col_l] = f;
                p_lds[idx64(row_l, col_l)] = __float2bfloat16(f);
            }
        __syncthreads();  // b2: VT + P ready (K reads done)

        // PV: wave w owns local d-slice [32w, 32w+32)
        bf16x8 pf[4][2];
        #pragma unroll
        for (int qt = 0; qt < 4; ++qt)
            #pragma unroll
            for (int ks = 0; ks < 2; ++ks)
                pf[qt][ks] = *(const bf16x8*)&p_lds[idx64(qt * 16 + lr, ks * 32 + lg * 8)];
        __builtin_amdgcn_s_setprio(1);
        #pragma unroll
        for (int dt = 0; dt < 2; ++dt)
            #pragma unroll
            for (int ks = 0; ks < 2; ++ks) {
                bf16x8 vf = *(const bf16x8*)&vt_lds[idx64(w * 32 + dt * 16 + lr, ks * 32 + lg * 8)];
                #pragma unroll
                for (int qt = 0; qt < 4; ++qt)
                    oacc[qt][dt] = MFMA16(pf[qt][ks], vf, oacc[qt][dt]);
            }
        __builtin_amdgcn_s_setprio(0);
    }

    // epilogue: out[B][S][D] fp32, this block's d-half
    #pragma unroll
    for (int qt = 0; qt < 4; ++qt)
        #pragma unroll
        for (int dt = 0; dt < 2; ++dt) {
            int col = dh * 256 + w * 32 + dt * 16 + lr;
            #pragma unroll
            for (int r = 0; r < 4; ++r) {
                int row = q0 + qt * 16 + lg * 4 + r;
                out[((size_t)(b * S + row)) * Dm + col] = oacc[qt][dt][r];
            }
        }
}

// ---------------------------------------------------------------------------
extern "C" void kernel_launch(void* const* d_in, const int* in_sizes, int n_in,
                              void* d_out, int out_size, void* d_ws, size_t ws_size,
                              hipStream_t stream) {
    const float* x  = (const float*)d_in[0];
    const float* Wq = (const float*)d_in[1];
    const float* bq = (const float*)d_in[2];
    const float* Wk = (const float*)d_in[3];
    const float* bk = (const float*)d_in[4];
    const float* Wv = (const float*)d_in[5];
    const float* bv = (const float*)d_in[6];

    float* out  = (float*)d_out;                      // [4,4096,512]
    float* attn = out + (size_t)Bb * S * Dm;          // [4,4096,4096]

    __hip_bfloat16* q_ws  = (__hip_bfloat16*)d_ws;              // [B][S][H]
    __hip_bfloat16* k_ws  = q_ws + (size_t)Bb * S * Hh;         // [B][S][H]
    __hip_bfloat16* vt_ws = k_ws + (size_t)Bb * S * Hh;         // [B][D][S]
    float*          l_ws  = (float*)(vt_ws + (size_t)Bb * Dm * S); // [B][S][4]

    const float scale = 0.0625f;  // 1/sqrt(256)

    proj_kernel<<<dim3(Hh / 64, (Bb * S) / 64), 256, 0, stream>>>(x, Wq, bq, q_ws, Hh, scale, 0);
    proj_kernel<<<dim3(Hh / 64, (Bb * S) / 64), 256, 0, stream>>>(x, Wk, bk, k_ws, Hh, 1.0f, 0);
    proj_kernel<<<dim3(Dm / 64, (Bb * S) / 64), 256, 0, stream>>>(x, Wv, bv, vt_ws, Dm, 1.0f, 1);

    lsum_kernel<<<512, 512, 0, stream>>>(q_ws, k_ws, l_ws);
    pv_kernel<<<512, 512, 0, stream>>>(q_ws, k_ws, vt_ws, l_ws, out, attn);
}